// Round 1
// baseline (1330.889 us; speedup 1.0000x reference)
//
#include <hip/hip_runtime.h>

#define N_NODES 100000
#define N_EDGES 1600000
#define D 64

__device__ __forceinline__ float bcast_lane(float v, int k) {
    return __int_as_float(__builtin_amdgcn_readlane(__float_as_int(v), k));
}

// ---- degree histogram (int atomics), then dinv = rsqrt(deg+1) in place ----
__global__ void k_count(const int* __restrict__ dst, int* __restrict__ deg) {
    int i = blockIdx.x * blockDim.x + threadIdx.x;
    if (i < N_EDGES) atomicAdd(&deg[dst[i]], 1);
}

__global__ void k_dinv(float* __restrict__ dinv) {
    int i = blockIdx.x * blockDim.x + threadIdx.x;
    if (i < N_NODES) {
        int c = ((const int*)dinv)[i];
        dinv[i] = rsqrtf((float)c + 1.0f);
    }
}

// ---- h = x @ W : one wave per row, W column held in 64 VGPRs per lane ----
__global__ __launch_bounds__(256) void k_gemm(const float* __restrict__ x,
                                              const float* __restrict__ W,
                                              float* __restrict__ h, int nrows) {
    const int lane = threadIdx.x & 63;
    // lane d owns column d of W (64 regs). Coalesced loads, L1-hit after warmup.
    float wcol[64];
#pragma unroll
    for (int k = 0; k < 64; ++k) wcol[k] = W[k * 64 + lane];

    int wave = (blockIdx.x * blockDim.x + threadIdx.x) >> 6;
    int nwaves = (gridDim.x * blockDim.x) >> 6;
    for (int row = wave; row < nrows; row += nwaves) {
        float xv = x[(size_t)row * 64 + lane];  // lane k holds x[row][k]
        float a0 = 0.f, a1 = 0.f;
#pragma unroll
        for (int k = 0; k < 64; k += 2) {
            a0 = fmaf(bcast_lane(xv, k), wcol[k], a0);
            a1 = fmaf(bcast_lane(xv, k + 1), wcol[k + 1], a1);
        }
        h[(size_t)row * 64 + lane] = a0 + a1;
    }
}

// ---- edge scatter: one wave per edge, lane = feature dim ----
__global__ __launch_bounds__(256) void k_scatter(const int* __restrict__ src,
                                                 const int* __restrict__ dst,
                                                 const float* __restrict__ dinv,
                                                 const float* __restrict__ h,
                                                 float* __restrict__ agg) {
    int e = (blockIdx.x * blockDim.x + threadIdx.x) >> 6;
    if (e >= N_EDGES) return;
    int lane = threadIdx.x & 63;
    int s = src[e];
    int d = dst[e];
    float norm = dinv[s] * dinv[d];
    float v = h[(size_t)s * 64 + lane] * norm;
    atomicAdd(&agg[(size_t)d * 64 + lane], v);
}

// ---- out = [relu](agg + h*dinv^2 + b) ; out may alias h (same-index) ----
__global__ void k_finish(const float* __restrict__ agg, const float* __restrict__ h,
                         const float* __restrict__ dinv, const float* __restrict__ b,
                         float* __restrict__ out, int relu) {
    int idx = blockIdx.x * blockDim.x + threadIdx.x;
    if (idx < N_NODES * 64) {
        int node = idx >> 6;
        float di = dinv[node];
        float v = agg[idx] + h[idx] * di * di + b[idx & 63];
        out[idx] = relu ? fmaxf(v, 0.f) : v;
    }
}

extern "C" void kernel_launch(void* const* d_in, const int* in_sizes, int n_in,
                              void* d_out, int out_size, void* d_ws, size_t ws_size,
                              hipStream_t stream) {
    const float* z  = (const float*)d_in[0];
    const int* src  = (const int*)d_in[1];
    const int* dst  = (const int*)d_in[2];
    const float* W1 = (const float*)d_in[3];
    const float* b1 = (const float*)d_in[4];
    const float* W2 = (const float*)d_in[5];
    const float* b2 = (const float*)d_in[6];
    const float* W3 = (const float*)d_in[7];
    const float* b3 = (const float*)d_in[8];
    float* out = (float*)d_out;

    char* ws = (char*)d_ws;
    float* dinv = (float*)ws;                       // 100000 floats (as int deg first)
    float* buf0 = (float*)(ws + (512 << 10));       // 25.6 MB
    float* buf1 = buf0 + (size_t)N_NODES * D;       // 25.6 MB
    float* agg  = buf1 + (size_t)N_NODES * D;       // 25.6 MB

    const size_t feat_bytes = (size_t)N_NODES * D * sizeof(float);
    const int gE  = (N_EDGES + 255) / 256;
    const int gN  = (N_NODES + 255) / 256;
    const int gF  = (N_NODES * D + 255) / 256;
    const int gSc = (N_EDGES * 64) / 256;  // one wave per edge

    // degrees -> dinv (graph fixed across layers)
    hipMemsetAsync(dinv, 0, N_NODES * sizeof(int), stream);
    k_count<<<gE, 256, 0, stream>>>(dst, (int*)dinv);
    k_dinv<<<gN, 256, 0, stream>>>(dinv);

    // ---- layer 1: buf0 = relu(gcn(z, W1, b1)) ----
    k_gemm<<<1024, 256, 0, stream>>>(z, W1, buf0, N_NODES);
    hipMemsetAsync(agg, 0, feat_bytes, stream);
    k_scatter<<<gSc, 256, 0, stream>>>(src, dst, dinv, buf0, agg);
    k_finish<<<gF, 256, 0, stream>>>(agg, buf0, dinv, b1, buf0, 1);

    // ---- layer 2: buf1 = relu(gcn(buf0, W2, b2)) ----
    k_gemm<<<1024, 256, 0, stream>>>(buf0, W2, buf1, N_NODES);
    hipMemsetAsync(agg, 0, feat_bytes, stream);
    k_scatter<<<gSc, 256, 0, stream>>>(src, dst, dinv, buf1, agg);
    k_finish<<<gF, 256, 0, stream>>>(agg, buf1, dinv, b2, buf1, 1);

    // ---- layer 3: out = gcn(buf1, W3, b3) ----
    k_gemm<<<1024, 256, 0, stream>>>(buf1, W3, buf0, N_NODES);
    hipMemsetAsync(agg, 0, feat_bytes, stream);
    k_scatter<<<gSc, 256, 0, stream>>>(src, dst, dinv, buf0, agg);
    k_finish<<<gF, 256, 0, stream>>>(agg, buf0, dinv, b3, out, 0);
}

// Round 2
// 548.965 us; speedup vs baseline: 2.4244x; 2.4244x over previous
//
#include <hip/hip_runtime.h>

#define N_NODES 100000
#define N_EDGES 1600000
#define D 64
#define SCAN_B 1024
#define NB ((N_NODES + SCAN_B - 1) / SCAN_B)  // 98

__device__ __forceinline__ float bcast_lane(float v, int k) {
    return __int_as_float(__builtin_amdgcn_readlane(__float_as_int(v), k));
}

// ---- degree histogram (int atomics) ----
__global__ void k_count(const int* __restrict__ dst, int* __restrict__ deg) {
    int i = blockIdx.x * blockDim.x + threadIdx.x;
    if (i < N_EDGES) atomicAdd(&deg[dst[i]], 1);
}

__global__ void k_dinv(const int* __restrict__ deg, float* __restrict__ dinv) {
    int i = blockIdx.x * blockDim.x + threadIdx.x;
    if (i < N_NODES) dinv[i] = rsqrtf((float)deg[i] + 1.0f);
}

// ---- 3-phase exclusive scan of deg -> rowptr (and cursor copy) ----
__global__ __launch_bounds__(SCAN_B) void k_scan1(const int* __restrict__ deg,
                                                  int* __restrict__ excl,
                                                  int* __restrict__ bsum) {
    __shared__ int sm[SCAN_B];
    int t = threadIdx.x;
    int i = blockIdx.x * SCAN_B + t;
    int v = (i < N_NODES) ? deg[i] : 0;
    sm[t] = v;
    __syncthreads();
    for (int off = 1; off < SCAN_B; off <<= 1) {
        int u = (t >= off) ? sm[t - off] : 0;
        __syncthreads();
        sm[t] += u;
        __syncthreads();
    }
    if (i < N_NODES) excl[i] = sm[t] - v;  // block-local exclusive
    if (t == SCAN_B - 1) bsum[blockIdx.x] = sm[t];
}

__global__ __launch_bounds__(128) void k_scan2(int* __restrict__ bsum) {
    __shared__ int sm[128];
    int t = threadIdx.x;
    int v = (t < NB) ? bsum[t] : 0;
    sm[t] = v;
    __syncthreads();
    for (int off = 1; off < 128; off <<= 1) {
        int u = (t >= off) ? sm[t - off] : 0;
        __syncthreads();
        sm[t] += u;
        __syncthreads();
    }
    if (t < NB) bsum[t] = sm[t] - v;  // exclusive block offsets
}

__global__ __launch_bounds__(SCAN_B) void k_scan3(int* __restrict__ rowptr,
                                                  int* __restrict__ cursor,
                                                  const int* __restrict__ bsum) {
    int i = blockIdx.x * SCAN_B + threadIdx.x;
    if (i < N_NODES) {
        int r = rowptr[i] + bsum[blockIdx.x];
        rowptr[i] = r;
        cursor[i] = r;
    }
    if (i == 0) rowptr[N_NODES] = N_EDGES;
}

// ---- bucket edges by dst: col[p] = src ----
__global__ void k_place(const int* __restrict__ src, const int* __restrict__ dst,
                        int* __restrict__ cursor, int* __restrict__ col) {
    int e = blockIdx.x * blockDim.x + threadIdx.x;
    if (e < N_EDGES) {
        int p = atomicAdd(&cursor[dst[e]], 1);
        col[p] = src[e];
    }
}

// ---- hs = (x @ W) * dinv[row] : one wave per row, W col in 64 VGPRs ----
__global__ __launch_bounds__(256) void k_gemm(const float* __restrict__ x,
                                              const float* __restrict__ W,
                                              const float* __restrict__ dinv,
                                              float* __restrict__ hs) {
    const int lane = threadIdx.x & 63;
    float wcol[64];
#pragma unroll
    for (int k = 0; k < 64; ++k) wcol[k] = W[k * 64 + lane];

    int wave = (blockIdx.x * blockDim.x + threadIdx.x) >> 6;
    int nwaves = (gridDim.x * blockDim.x) >> 6;
    for (int row = wave; row < N_NODES; row += nwaves) {
        float xv = x[(size_t)row * 64 + lane];
        float a0 = 0.f, a1 = 0.f;
#pragma unroll
        for (int k = 0; k < 64; k += 2) {
            a0 = fmaf(bcast_lane(xv, k), wcol[k], a0);
            a1 = fmaf(bcast_lane(xv, k + 1), wcol[k + 1], a1);
        }
        hs[(size_t)row * 64 + lane] = (a0 + a1) * dinv[row];
    }
}

// ---- gather-aggregate + fused epilogue:
//      out[d] = [relu]( dinv[d] * (sum_{s in N(d)} hs[s] + hs[d]) + b ) ----
__global__ __launch_bounds__(256) void k_agg(const int* __restrict__ rowptr,
                                             const int* __restrict__ col,
                                             const float* __restrict__ dinv,
                                             const float* __restrict__ hs,
                                             const float* __restrict__ b,
                                             float* __restrict__ out, int relu) {
    int w = (blockIdx.x * blockDim.x + threadIdx.x) >> 6;
    if (w >= N_NODES) return;
    int node = __builtin_amdgcn_readfirstlane(w);  // force wave-uniform -> s_loads
    int lane = threadIdx.x & 63;
    int beg = rowptr[node], end = rowptr[node + 1];

    float a0 = 0.f, a1 = 0.f, a2 = 0.f, a3 = 0.f;
    int e = beg;
    for (; e + 3 < end; e += 4) {
        int s0 = col[e], s1 = col[e + 1], s2 = col[e + 2], s3 = col[e + 3];
        a0 += hs[s0 * 64 + lane];
        a1 += hs[s1 * 64 + lane];
        a2 += hs[s2 * 64 + lane];
        a3 += hs[s3 * 64 + lane];
    }
    for (; e < end; ++e) a0 += hs[col[e] * 64 + lane];

    float acc = (a0 + a1) + (a2 + a3) + hs[node * 64 + lane];
    float v = fmaf(acc, dinv[node], b[lane]);
    out[(size_t)node * 64 + lane] = relu ? fmaxf(v, 0.f) : v;
}

extern "C" void kernel_launch(void* const* d_in, const int* in_sizes, int n_in,
                              void* d_out, int out_size, void* d_ws, size_t ws_size,
                              hipStream_t stream) {
    const float* z  = (const float*)d_in[0];
    const int* src  = (const int*)d_in[1];
    const int* dst  = (const int*)d_in[2];
    const float* W1 = (const float*)d_in[3];
    const float* b1 = (const float*)d_in[4];
    const float* W2 = (const float*)d_in[5];
    const float* b2 = (const float*)d_in[6];
    const float* W3 = (const float*)d_in[7];
    const float* b3 = (const float*)d_in[8];
    float* out = (float*)d_out;

    char* p = (char*)d_ws;
    int*   deg    = (int*)p;    p += (size_t)512 << 10;
    float* dinv   = (float*)p;  p += (size_t)512 << 10;
    int*   rowptr = (int*)p;    p += (size_t)512 << 10;  // N_NODES+1
    int*   cursor = (int*)p;    p += (size_t)512 << 10;
    int*   bsum   = (int*)p;    p += (size_t)4 << 10;    // NB=98 ints
    int*   col    = (int*)p;    p += (size_t)8 << 20;    // 6.4 MB used
    float* buf0   = (float*)p;  p += (size_t)32 << 20;   // 25.6 MB used
    float* buf1   = (float*)p;  /* 25.6 MB */

    const int gE = (N_EDGES + 255) / 256;
    const int gN = (N_NODES + 255) / 256;
    const int gA = (N_NODES * 64) / 256 + 1;  // one wave per node

    // ---- CSR build (once; graph shared by all 3 layers) ----
    hipMemsetAsync(deg, 0, N_NODES * sizeof(int), stream);
    k_count<<<gE, 256, 0, stream>>>(dst, deg);
    k_dinv<<<gN, 256, 0, stream>>>(deg, dinv);
    k_scan1<<<NB, SCAN_B, 0, stream>>>(deg, rowptr, bsum);
    k_scan2<<<1, 128, 0, stream>>>(bsum);
    k_scan3<<<NB, SCAN_B, 0, stream>>>(rowptr, cursor, bsum);
    k_place<<<gE, 256, 0, stream>>>(src, dst, cursor, col);

    // ---- layer 1 ----
    k_gemm<<<1024, 256, 0, stream>>>(z, W1, dinv, buf0);
    k_agg<<<gA, 256, 0, stream>>>(rowptr, col, dinv, buf0, b1, buf1, 1);
    // ---- layer 2 ----
    k_gemm<<<1024, 256, 0, stream>>>(buf1, W2, dinv, buf0);
    k_agg<<<gA, 256, 0, stream>>>(rowptr, col, dinv, buf0, b2, buf1, 1);
    // ---- layer 3 ----
    k_gemm<<<1024, 256, 0, stream>>>(buf1, W3, dinv, buf0);
    k_agg<<<gA, 256, 0, stream>>>(rowptr, col, dinv, buf0, b3, out, 0);
}

// Round 3
// 547.508 us; speedup vs baseline: 2.4308x; 1.0027x over previous
//
#include <hip/hip_runtime.h>

#define N_NODES 100000
#define N_EDGES 1600000
#define D 64
#define SCAN_B 1024
#define NB ((N_NODES + SCAN_B - 1) / SCAN_B)  // 98
#define PLACE_CHUNKS 128
#define PART_SZ 12500  // N_NODES / 8

__device__ __forceinline__ float bcast_lane(float v, int k) {
    return __int_as_float(__builtin_amdgcn_readlane(__float_as_int(v), k));
}

// ---- degree histogram (int atomics) ----
__global__ void k_count(const int* __restrict__ dst, int* __restrict__ deg) {
    int i = blockIdx.x * blockDim.x + threadIdx.x;
    if (i < N_EDGES) atomicAdd(&deg[dst[i]], 1);
}

__global__ void k_dinv(const int* __restrict__ deg, float* __restrict__ dinv) {
    int i = blockIdx.x * blockDim.x + threadIdx.x;
    if (i < N_NODES) dinv[i] = rsqrtf((float)deg[i] + 1.0f);
}

// ---- xs = z * dinv[row]  (float4 vectorized) ----
__global__ void k_scale(const float* __restrict__ z, const float* __restrict__ dinv,
                        float* __restrict__ xs) {
    int idx = blockIdx.x * blockDim.x + threadIdx.x;  // over N_NODES*16 float4s
    if (idx < N_NODES * 16) {
        float4 v = ((const float4*)z)[idx];
        float d = dinv[idx >> 4];
        v.x *= d; v.y *= d; v.z *= d; v.w *= d;
        ((float4*)xs)[idx] = v;
    }
}

// ---- 3-phase exclusive scan of deg -> rowptr (and cursor copy) ----
__global__ __launch_bounds__(SCAN_B) void k_scan1(const int* __restrict__ deg,
                                                  int* __restrict__ excl,
                                                  int* __restrict__ bsum) {
    __shared__ int sm[SCAN_B];
    int t = threadIdx.x;
    int i = blockIdx.x * SCAN_B + t;
    int v = (i < N_NODES) ? deg[i] : 0;
    sm[t] = v;
    __syncthreads();
    for (int off = 1; off < SCAN_B; off <<= 1) {
        int u = (t >= off) ? sm[t - off] : 0;
        __syncthreads();
        sm[t] += u;
        __syncthreads();
    }
    if (i < N_NODES) excl[i] = sm[t] - v;
    if (t == SCAN_B - 1) bsum[blockIdx.x] = sm[t];
}

__global__ __launch_bounds__(128) void k_scan2(int* __restrict__ bsum) {
    __shared__ int sm[128];
    int t = threadIdx.x;
    int v = (t < NB) ? bsum[t] : 0;
    sm[t] = v;
    __syncthreads();
    for (int off = 1; off < 128; off <<= 1) {
        int u = (t >= off) ? sm[t - off] : 0;
        __syncthreads();
        sm[t] += u;
        __syncthreads();
    }
    if (t < NB) bsum[t] = sm[t] - v;
}

__global__ __launch_bounds__(SCAN_B) void k_scan3(int* __restrict__ rowptr,
                                                  int* __restrict__ cursor,
                                                  const int* __restrict__ bsum) {
    int i = blockIdx.x * SCAN_B + threadIdx.x;
    if (i < N_NODES) {
        int r = rowptr[i] + bsum[blockIdx.x];
        rowptr[i] = r;
        cursor[i] = r;
    }
    if (i == 0) rowptr[N_NODES] = N_EDGES;
}

// ---- XCD-partitioned bucket: block b handles chunk b>>3, dst-range b&7.
//      Each col[] line is then written by one XCD class only -> L2-local
//      accumulation, single drain (vs 16x write amplification). ----
__global__ __launch_bounds__(256) void k_place(const int* __restrict__ src,
                                               const int* __restrict__ dst,
                                               int* __restrict__ cursor,
                                               int* __restrict__ col) {
    int part = blockIdx.x & 7;          // consecutive blocks -> different XCDs
    int chunk = blockIdx.x >> 3;
    const int CS = N_EDGES / PLACE_CHUNKS;  // 12500
    int base = chunk * CS;
    for (int e = base + threadIdx.x; e < base + CS; e += 256) {
        int d = dst[e];
        if ((unsigned)d / PART_SZ == (unsigned)part) {
            int p = atomicAdd(&cursor[d], 1);
            col[p] = src[e];
        }
    }
}

// ---- fused layer: out = epi( dinv[d]*(sum_{s in N(d)} xs[s] + xs[d]) @ W + b )
//      epi = relu*dinv (hidden) or identity (final).
//      One persistent wave per node (grid-stride); W column in 64 VGPRs;
//      gather: 16 lanes x float4 x 4 edges per VMEM instr. ----
__global__ __launch_bounds__(256) void k_layer(const int* __restrict__ rowptr,
                                               const int* __restrict__ col,
                                               const float* __restrict__ dinv,
                                               const float* __restrict__ xs,
                                               const float* __restrict__ W,
                                               const float* __restrict__ bias,
                                               float* __restrict__ out, int hidden) {
    const int lane = threadIdx.x & 63;
    const int quarter = lane >> 4;  // which of 4 edges in a quad
    const int fl = lane & 15;       // which float4 of the row

    float wcol[64];
#pragma unroll
    for (int k = 0; k < 64; ++k) wcol[k] = W[k * 64 + lane];
    const float bv = bias[lane];

    int wave = (blockIdx.x * blockDim.x + threadIdx.x) >> 6;
    int nwaves = (gridDim.x * blockDim.x) >> 6;

    for (int node = wave; node < N_NODES; node += nwaves) {
        int un = __builtin_amdgcn_readfirstlane(node);
        int beg = rowptr[un], end = rowptr[un + 1];

        float4 a0 = {0.f, 0.f, 0.f, 0.f};
        float4 a1 = {0.f, 0.f, 0.f, 0.f};
        for (int e = beg; e < end; e += 8) {
            int eA = e + quarter, eB = e + 4 + quarter;
            if (eA < end) {
                int s = col[eA];
                float4 v = *(const float4*)(xs + (size_t)s * 64 + fl * 4);
                a0.x += v.x; a0.y += v.y; a0.z += v.z; a0.w += v.w;
            }
            if (eB < end) {
                int s = col[eB];
                float4 v = *(const float4*)(xs + (size_t)s * 64 + fl * 4);
                a1.x += v.x; a1.y += v.y; a1.z += v.z; a1.w += v.w;
            }
        }
        float4 acc;
        acc.x = a0.x + a1.x; acc.y = a0.y + a1.y;
        acc.z = a0.z + a1.z; acc.w = a0.w + a1.w;
        // butterfly-reduce the 4 quarter partials (features identical per fl)
#pragma unroll
        for (int m = 16; m <= 32; m <<= 1) {
            acc.x += __shfl_xor(acc.x, m, 64);
            acc.y += __shfl_xor(acc.y, m, 64);
            acc.z += __shfl_xor(acc.z, m, 64);
            acc.w += __shfl_xor(acc.w, m, 64);
        }
        // self-loop term + dinv[d] scale
        float4 sv = *(const float4*)(xs + (size_t)un * 64 + fl * 4);
        float di = dinv[un];
        acc.x = (acc.x + sv.x) * di; acc.y = (acc.y + sv.y) * di;
        acc.z = (acc.z + sv.z) * di; acc.w = (acc.w + sv.w) * di;

        // in-register matvec: o[lane] = sum_k acc_feat[k] * W[k][lane] + b
        float o = bv;
#pragma unroll
        for (int k = 0; k < 64; ++k) {
            float comp = ((k & 3) == 0) ? acc.x : ((k & 3) == 1) ? acc.y
                         : ((k & 3) == 2) ? acc.z : acc.w;
            o = fmaf(bcast_lane(comp, k >> 2), wcol[k], o);
        }
        if (hidden) o = fmaxf(o, 0.f) * di;  // pre-scale for next layer's gather
        out[(size_t)un * 64 + lane] = o;
    }
}

extern "C" void kernel_launch(void* const* d_in, const int* in_sizes, int n_in,
                              void* d_out, int out_size, void* d_ws, size_t ws_size,
                              hipStream_t stream) {
    const float* z  = (const float*)d_in[0];
    const int* src  = (const int*)d_in[1];
    const int* dst  = (const int*)d_in[2];
    const float* W1 = (const float*)d_in[3];
    const float* b1 = (const float*)d_in[4];
    const float* W2 = (const float*)d_in[5];
    const float* b2 = (const float*)d_in[6];
    const float* W3 = (const float*)d_in[7];
    const float* b3 = (const float*)d_in[8];
    float* out = (float*)d_out;

    char* p = (char*)d_ws;
    int*   deg    = (int*)p;    p += (size_t)512 << 10;
    float* dinv   = (float*)p;  p += (size_t)512 << 10;
    int*   rowptr = (int*)p;    p += (size_t)512 << 10;  // N_NODES+1
    int*   cursor = (int*)p;    p += (size_t)512 << 10;
    int*   bsum   = (int*)p;    p += (size_t)4 << 10;    // NB=98 ints
    int*   col    = (int*)p;    p += (size_t)8 << 20;    // 6.4 MB used
    float* buf0   = (float*)p;  p += (size_t)32 << 20;   // 25.6 MB used
    float* buf1   = (float*)p;  /* 25.6 MB */

    const int gE = (N_EDGES + 255) / 256;
    const int gN = (N_NODES + 255) / 256;
    const int gS = (N_NODES * 16 + 255) / 256;
    const int gL = 1024;  // persistent: 4096 waves, ~24 nodes/wave

    // ---- CSR build (once; graph shared by all 3 layers) ----
    hipMemsetAsync(deg, 0, N_NODES * sizeof(int), stream);
    k_count<<<gE, 256, 0, stream>>>(dst, deg);
    k_dinv<<<gN, 256, 0, stream>>>(deg, dinv);
    k_scan1<<<NB, SCAN_B, 0, stream>>>(deg, rowptr, bsum);
    k_scan2<<<1, 128, 0, stream>>>(bsum);
    k_scan3<<<NB, SCAN_B, 0, stream>>>(rowptr, cursor, bsum);
    k_place<<<PLACE_CHUNKS * 8, 256, 0, stream>>>(src, dst, cursor, col);

    // ---- xs0 = z * dinv ----
    k_scale<<<gS, 256, 0, stream>>>(z, dinv, buf0);

    // ---- 3 fused layers ----
    k_layer<<<gL, 256, 0, stream>>>(rowptr, col, dinv, buf0, W1, b1, buf1, 1);
    k_layer<<<gL, 256, 0, stream>>>(rowptr, col, dinv, buf1, W2, b2, buf0, 1);
    k_layer<<<gL, 256, 0, stream>>>(rowptr, col, dinv, buf0, W3, b3, out, 0);
}

// Round 4
// 468.184 us; speedup vs baseline: 2.8427x; 1.1694x over previous
//
#include <hip/hip_runtime.h>

#define N_NODES 100000
#define N_EDGES 1600000
#define D 64
#define SCAN_B 1024
#define NB ((N_NODES + SCAN_B - 1) / SCAN_B)  // 98
#define PLACE_CHUNKS 128
#define PART_SZ 12500  // N_NODES / 8

__device__ __forceinline__ float bcast_lane(float v, int k) {
    return __int_as_float(__builtin_amdgcn_readlane(__float_as_int(v), k));
}

// ---- degree histogram (int atomics) ----
__global__ void k_count(const int* __restrict__ dst, int* __restrict__ deg) {
    int i = blockIdx.x * blockDim.x + threadIdx.x;
    if (i < N_EDGES) atomicAdd(&deg[dst[i]], 1);
}

// ---- xs = z * dinv[row]  (float4 vectorized) ----
__global__ void k_scale(const float* __restrict__ z, const float* __restrict__ dinv,
                        float* __restrict__ xs) {
    int idx = blockIdx.x * blockDim.x + threadIdx.x;  // over N_NODES*16 float4s
    if (idx < N_NODES * 16) {
        float4 v = ((const float4*)z)[idx];
        float d = dinv[idx >> 4];
        v.x *= d; v.y *= d; v.z *= d; v.w *= d;
        ((float4*)xs)[idx] = v;
    }
}

// ---- scan phase 1 (+ fused dinv) ----
__global__ __launch_bounds__(SCAN_B) void k_scan1(const int* __restrict__ deg,
                                                  int* __restrict__ excl,
                                                  int* __restrict__ bsum,
                                                  float* __restrict__ dinv) {
    __shared__ int sm[SCAN_B];
    int t = threadIdx.x;
    int i = blockIdx.x * SCAN_B + t;
    int v = (i < N_NODES) ? deg[i] : 0;
    if (i < N_NODES) dinv[i] = rsqrtf((float)v + 1.0f);
    sm[t] = v;
    __syncthreads();
    for (int off = 1; off < SCAN_B; off <<= 1) {
        int u = (t >= off) ? sm[t - off] : 0;
        __syncthreads();
        sm[t] += u;
        __syncthreads();
    }
    if (i < N_NODES) excl[i] = sm[t] - v;
    if (t == SCAN_B - 1) bsum[blockIdx.x] = sm[t];
}

__global__ __launch_bounds__(128) void k_scan2(int* __restrict__ bsum) {
    __shared__ int sm[128];
    int t = threadIdx.x;
    int v = (t < NB) ? bsum[t] : 0;
    sm[t] = v;
    __syncthreads();
    for (int off = 1; off < 128; off <<= 1) {
        int u = (t >= off) ? sm[t - off] : 0;
        __syncthreads();
        sm[t] += u;
        __syncthreads();
    }
    if (t < NB) bsum[t] = sm[t] - v;
}

__global__ __launch_bounds__(SCAN_B) void k_scan3(int* __restrict__ rowptr,
                                                  int* __restrict__ cursor,
                                                  const int* __restrict__ bsum) {
    int i = blockIdx.x * SCAN_B + threadIdx.x;
    if (i < N_NODES) {
        int r = rowptr[i] + bsum[blockIdx.x];
        rowptr[i] = r;
        cursor[i] = r;
    }
    if (i == 0) rowptr[N_NODES] = N_EDGES;
}

// ---- XCD-partitioned bucket: block b handles chunk b>>3, dst-range b&7. ----
__global__ __launch_bounds__(256) void k_place(const int* __restrict__ src,
                                               const int* __restrict__ dst,
                                               int* __restrict__ cursor,
                                               int* __restrict__ col) {
    int part = blockIdx.x & 7;          // consecutive blocks -> different XCDs
    int chunk = blockIdx.x >> 3;
    const int CS = N_EDGES / PLACE_CHUNKS;  // 12500
    int base = chunk * CS;
    for (int e = base + threadIdx.x; e < base + CS; e += 256) {
        int d = dst[e];
        if ((unsigned)d / PART_SZ == (unsigned)part) {
            int p = atomicAdd(&cursor[d], 1);
            col[p] = src[e];
        }
    }
}

// ---- fused layer: out = epi( dinv[d]*(sum_{s in N(d)} xs[s] + xs[d]) @ W + b )
//      One wave per node; 16 lanes x float4 per row; 4 rows (quarters) and
//      4 unrolled edge-quads per iteration -> 4 independent gathers in flight. ----
__global__ __launch_bounds__(256) void k_layer(const int* __restrict__ rowptr,
                                               const int* __restrict__ col,
                                               const float* __restrict__ dinv,
                                               const float* __restrict__ xs,
                                               const float* __restrict__ W,
                                               const float* __restrict__ bias,
                                               float* __restrict__ out, int hidden) {
    const int lane = threadIdx.x & 63;
    const int quarter = lane >> 4;  // which edge within a quad
    const int fl = lane & 15;       // which float4 of the row

    float wcol[64];
#pragma unroll
    for (int k = 0; k < 64; ++k) wcol[k] = W[k * 64 + lane];
    const float bv = bias[lane];

    int wave = (blockIdx.x * blockDim.x + threadIdx.x) >> 6;
    int nwaves = (gridDim.x * blockDim.x) >> 6;

    for (int node = wave; node < N_NODES; node += nwaves) {
        int un = __builtin_amdgcn_readfirstlane(node);
        int beg = rowptr[un], end = rowptr[un + 1];

        float4 acc = {0.f, 0.f, 0.f, 0.f};
        for (int e = beg; e < end; e += 16) {
            // 16 edges per iter: 4 independent (col -> xs) gather chains
            int e0 = e + quarter, e1 = e0 + 4, e2 = e0 + 8, e3 = e0 + 12;
            int i0 = col[e0 < end ? e0 : end - 1];
            int i1 = col[e1 < end ? e1 : end - 1];
            int i2 = col[e2 < end ? e2 : end - 1];
            int i3 = col[e3 < end ? e3 : end - 1];
            float4 v0 = *(const float4*)(xs + (size_t)i0 * 64 + fl * 4);
            float4 v1 = *(const float4*)(xs + (size_t)i1 * 64 + fl * 4);
            float4 v2 = *(const float4*)(xs + (size_t)i2 * 64 + fl * 4);
            float4 v3 = *(const float4*)(xs + (size_t)i3 * 64 + fl * 4);
            if (e0 < end) { acc.x += v0.x; acc.y += v0.y; acc.z += v0.z; acc.w += v0.w; }
            if (e1 < end) { acc.x += v1.x; acc.y += v1.y; acc.z += v1.z; acc.w += v1.w; }
            if (e2 < end) { acc.x += v2.x; acc.y += v2.y; acc.z += v2.z; acc.w += v2.w; }
            if (e3 < end) { acc.x += v3.x; acc.y += v3.y; acc.z += v3.z; acc.w += v3.w; }
        }
        // butterfly-reduce the 4 quarter partials (feature slot fl identical)
#pragma unroll
        for (int m = 16; m <= 32; m <<= 1) {
            acc.x += __shfl_xor(acc.x, m, 64);
            acc.y += __shfl_xor(acc.y, m, 64);
            acc.z += __shfl_xor(acc.z, m, 64);
            acc.w += __shfl_xor(acc.w, m, 64);
        }
        // self-loop term + dinv[d] scale
        float4 sv = *(const float4*)(xs + (size_t)un * 64 + fl * 4);
        float di = dinv[un];
        acc.x = (acc.x + sv.x) * di; acc.y = (acc.y + sv.y) * di;
        acc.z = (acc.z + sv.z) * di; acc.w = (acc.w + sv.w) * di;

        // in-register matvec, dual accumulator chains
        float o0 = bv, o1 = 0.f;
#pragma unroll
        for (int k = 0; k < 64; k += 2) {
            float c0 = ((k & 3) == 0) ? acc.x : acc.z;     // k even: x or z
            float c1 = (((k + 1) & 3) == 1) ? acc.y : acc.w;
            o0 = fmaf(bcast_lane(c0, k >> 2), wcol[k], o0);
            o1 = fmaf(bcast_lane(c1, (k + 1) >> 2), wcol[k + 1], o1);
        }
        float o = o0 + o1;
        if (hidden) o = fmaxf(o, 0.f) * di;  // pre-scale for next layer's gather
        out[(size_t)un * 64 + lane] = o;
    }
}

extern "C" void kernel_launch(void* const* d_in, const int* in_sizes, int n_in,
                              void* d_out, int out_size, void* d_ws, size_t ws_size,
                              hipStream_t stream) {
    const float* z  = (const float*)d_in[0];
    const int* src  = (const int*)d_in[1];
    const int* dst  = (const int*)d_in[2];
    const float* W1 = (const float*)d_in[3];
    const float* b1 = (const float*)d_in[4];
    const float* W2 = (const float*)d_in[5];
    const float* b2 = (const float*)d_in[6];
    const float* W3 = (const float*)d_in[7];
    const float* b3 = (const float*)d_in[8];
    float* out = (float*)d_out;

    char* p = (char*)d_ws;
    int*   deg    = (int*)p;    p += (size_t)512 << 10;
    float* dinv   = (float*)p;  p += (size_t)512 << 10;
    int*   rowptr = (int*)p;    p += (size_t)512 << 10;  // N_NODES+1
    int*   cursor = (int*)p;    p += (size_t)512 << 10;
    int*   bsum   = (int*)p;    p += (size_t)4 << 10;    // NB=98 ints
    int*   col    = (int*)p;    p += (size_t)8 << 20;    // 6.4 MB used
    float* buf0   = (float*)p;  p += (size_t)32 << 20;   // 25.6 MB used
    float* buf1   = (float*)p;  /* 25.6 MB */

    const int gE = (N_EDGES + 255) / 256;
    const int gS = (N_NODES * 16 + 255) / 256;
    const int gL = 2048;  // 8192 waves = full chip at VGPR<=64

    // ---- CSR build (once; graph shared by all 3 layers) ----
    hipMemsetAsync(deg, 0, N_NODES * sizeof(int), stream);
    k_count<<<gE, 256, 0, stream>>>(dst, deg);
    k_scan1<<<NB, SCAN_B, 0, stream>>>(deg, rowptr, bsum, dinv);
    k_scan2<<<1, 128, 0, stream>>>(bsum);
    k_scan3<<<NB, SCAN_B, 0, stream>>>(rowptr, cursor, bsum);
    k_place<<<PLACE_CHUNKS * 8, 256, 0, stream>>>(src, dst, cursor, col);

    // ---- xs0 = z * dinv ----
    k_scale<<<gS, 256, 0, stream>>>(z, dinv, buf0);

    // ---- 3 fused layers ----
    k_layer<<<gL, 256, 0, stream>>>(rowptr, col, dinv, buf0, W1, b1, buf1, 1);
    k_layer<<<gL, 256, 0, stream>>>(rowptr, col, dinv, buf1, W2, b2, buf0, 1);
    k_layer<<<gL, 256, 0, stream>>>(rowptr, col, dinv, buf0, W3, b3, out, 0);
}